// Round 5
// baseline (1178.666 us; speedup 1.0000x reference)
//
#include <hip/hip_runtime.h>
#include <math.h>

#define NN 50000
#define FD 8
#define TD 12
#define HD 64
#define FT 96            // FD*TD floats per node
#define EE 1600000
#define NBUK 391         // ceil(NN/128) dst buckets of 128 nodes
#define TILE 16384
#define NT 98            // ceil(EE/TILE)
#define STRIDE 100       // LDS agg row stride (pad vs bank conflicts, 16B-aligned)

// ws offsets (4B units)
#define OFF_GHIST 0                  // int[NBUK]
#define OFF_BASE  512                // int[NBUK+1]
#define OFF_CUR   1024               // int[NBUK]
#define OFF_DINV  2048               // float[NN]
#define OFF_FUSED (2048 + NN)        // float[1164]
#define OFF_BEDGE (2048 + NN + 1280) // int2[EE] (8B-aligned: offset is even)

__global__ void k_precompute(const float* __restrict__ conv_w,
                             const float* __restrict__ conv_b,
                             const float* __restrict__ lin_w,
                             const float* __restrict__ lin_b,
                             const float* __restrict__ attention,
                             float* __restrict__ fused) {
    int tid = threadIdx.x;
    // Wzz (0..511): f,h -> sum_k conv_w[f][k]    * lin_w[0][k][h]
    // Whh (512..1023):    sum_k conv_w[f][128+k] * lin_w[2][k][h]
    for (int idx = tid; idx < 1024; idx += blockDim.x) {
        int sel = idx >> 9;
        int f = (idx & 511) >> 6;
        int h = idx & 63;
        const float* cw = conv_w + f * 192 + (sel ? 128 : 0);
        const float* lw = lin_w + (sel ? 2 * 128 * 64 : 0) + h;
        float s = 0.f;
        for (int k = 0; k < 64; ++k) s += cw[k] * lw[k * 64];
        fused[idx] = s;
    }
    // bzz (1024..1087), bhh (1088..1151)
    for (int idx = tid; idx < 128; idx += blockDim.x) {
        int sel = idx >> 6;
        int h = idx & 63;
        const float* cb = conv_b + (sel ? 128 : 0);
        const float* lw = lin_w + (sel ? 2 * 128 * 64 : 0) + h;
        float s = lin_b[(sel ? 2 * 64 : 0) + h];
        for (int k = 0; k < 64; ++k) s += cb[k] * lw[k * 64];
        fused[1024 + idx] = s;
    }
    // probs (1152..1163): softmax(attention)
    if (tid == 0) {
        float m = attention[0];
        for (int t = 1; t < TD; ++t) m = fmaxf(m, attention[t]);
        float e[TD], sum = 0.f;
        for (int t = 0; t < TD; ++t) { e[t] = __expf(attention[t] - m); sum += e[t]; }
        for (int t = 0; t < TD; ++t) fused[1152 + t] = e[t] / sum;
    }
}

__global__ void k_zero(int* __restrict__ ghist) {
    int i = threadIdx.x;
    if (i < NBUK) ghist[i] = 0;
}

// LDS-aggregated bucket histogram: ~NBUK global atomics per tile (not per edge)
__global__ __launch_bounds__(1024) void k_hist(const int* __restrict__ ei,
                                               int* __restrict__ ghist) {
    __shared__ int h[NBUK];
    int tid = threadIdx.x;
    for (int i = tid; i < NBUK; i += 1024) h[i] = 0;
    __syncthreads();
    int base = blockIdx.x * TILE;
    for (int i = 0; i < TILE / 1024; ++i) {
        int e = base + i * 1024 + tid;
        if (e < EE) atomicAdd(&h[ei[EE + e] >> 7], 1);
    }
    __syncthreads();
    for (int i = tid; i < NBUK; i += 1024)
        if (h[i]) atomicAdd(&ghist[i], h[i]);
}

// exclusive scan of bucket counts -> bucket bases + append cursors
__global__ void k_scan(const int* __restrict__ ghist, int* __restrict__ bktbase,
                       int* __restrict__ cursor) {
    __shared__ int s[512];
    int tid = threadIdx.x;
    int v = (tid < NBUK) ? ghist[tid] : 0;
    s[tid] = v;
    __syncthreads();
    for (int off = 1; off < 512; off <<= 1) {
        int t = (tid >= off) ? s[tid - off] : 0;
        __syncthreads();
        s[tid] += t;
        __syncthreads();
    }
    int excl = s[tid] - v;
    if (tid < NBUK) { bktbase[tid] = excl; cursor[tid] = excl; }
    if (tid == NBUK - 1) bktbase[NBUK] = excl + v;   // == EE
}

// tile claims per-bucket ranges (one global atomic per (tile,bucket)), then
// writes packed edges grouped by bucket: (src | dst_local<<16, w)
__global__ __launch_bounds__(1024) void k_place(const int* __restrict__ ei,
                                                const float* __restrict__ w,
                                                int* __restrict__ cursor,
                                                int2* __restrict__ bedge) {
    __shared__ int h[NBUK], bbase[NBUK];
    int tid = threadIdx.x;
    for (int i = tid; i < NBUK; i += 1024) h[i] = 0;
    __syncthreads();
    int base = blockIdx.x * TILE;
    for (int i = 0; i < TILE / 1024; ++i) {
        int e = base + i * 1024 + tid;
        if (e < EE) atomicAdd(&h[ei[EE + e] >> 7], 1);
    }
    __syncthreads();
    for (int i = tid; i < NBUK; i += 1024) {
        int c = h[i];
        bbase[i] = c ? atomicAdd(&cursor[i], c) : 0;
        h[i] = 0;
    }
    __syncthreads();
    for (int i = 0; i < TILE / 1024; ++i) {
        int e = base + i * 1024 + tid;
        if (e < EE) {
            int dst = ei[EE + e];
            int bk = dst >> 7;
            int rank = atomicAdd(&h[bk], 1);   // LDS rank within (tile,bucket)
            bedge[bbase[bk] + rank] =
                make_int2(ei[e] | ((dst & 127) << 16), __float_as_int(w[e]));
        }
    }
}

// per-bucket weighted degree in LDS -> dinv (no global atomics)
__global__ __launch_bounds__(256) void k_deg(const int* __restrict__ bktbase,
                                             const int2* __restrict__ bedge,
                                             float* __restrict__ dinv) {
    __shared__ float wd[128];
    int tid = threadIdx.x, b = blockIdx.x;
    if (tid < 128) wd[tid] = 0.f;
    __syncthreads();
    int es = bktbase[b], ee = bktbase[b + 1];
    for (int i = es + tid; i < ee; i += 256) {
        int2 u = bedge[i];
        atomicAdd(&wd[u.x >> 16], __int_as_float(u.y));
    }
    __syncthreads();
    int dbase = b << 7;
    if (tid < 128 && dbase + tid < NN) dinv[dbase + tid] = rsqrtf(1.0f + wd[tid]);
}

// one block per bucket: LDS-accumulated SpMM + fused GRU/attention/classifier
__global__ __launch_bounds__(384) void k_spmm(const float* __restrict__ x,
                                              const float* __restrict__ dinv,
                                              const int* __restrict__ bktbase,
                                              const int2* __restrict__ bedge,
                                              const float* __restrict__ fused,
                                              const float* __restrict__ cls_w,
                                              const float* __restrict__ cls_b,
                                              float* __restrict__ out) {
    __shared__ float agg[128 * STRIDE];        // 51.2 KB
    __shared__ float sW[1164 + 768 + 12];      // 7.8 KB
    int tid = threadIdx.x, b = blockIdx.x;
    int dbase = b << 7;
    int nd = min(128, NN - dbase);
    for (int i = tid; i < 1164 + 768; i += 384)
        sW[i] = (i < 1164) ? fused[i] : cls_w[i - 1164];
    if (tid < 12) sW[1164 + 768 + tid] = cls_b[tid];
    const float4* x4 = (const float4*)x;

    // phase 0: self-loop term dinv[d]*x[d] (also zeroes/initializes agg rows)
    for (int u = tid; u < 128 * 24; u += 384) {
        int dl = u / 24;
        int c = u - dl * 24;
        if (dl < nd) {
            int d = dbase + dl;
            float dv = dinv[d];
            float4 v = x4[d * 24 + c];
            v.x *= dv; v.y *= dv; v.z *= dv; v.w *= dv;
            *(float4*)&agg[dl * STRIDE + 4 * c] = v;
        }
    }
    __syncthreads();

    // phase 1: edges -> LDS float atomics (16 edges in flight, 24 lanes each)
    int es = bktbase[b], ee = bktbase[b + 1];
    int c = tid % 24, eoff = tid / 24;
    for (int e0 = es; e0 < ee; e0 += 16) {
        int eidx = e0 + eoff;
        if (eidx < ee) {
            int2 u = bedge[eidx];
            int src = u.x & 0xFFFF;
            int dl = u.x >> 16;
            float co = dinv[src] * __int_as_float(u.y);
            float4 xv = x4[src * 24 + c];
            float* a = &agg[dl * STRIDE + 4 * c];
            atomicAdd(a + 0, co * xv.x);
            atomicAdd(a + 1, co * xv.y);
            atomicAdd(a + 2, co * xv.z);
            atomicAdd(a + 3, co * xv.w);
        }
    }
    __syncthreads();

    // phase 2: outer dinv scale + GRU gates + attention accum + ReLU + classifier
    if (tid < nd) {
        int d = dbase + tid;
        float dv = dinv[d];
        float r[FT];
#pragma unroll
        for (int i = 0; i < 24; ++i) {
            float4 v = *(float4*)&agg[tid * STRIDE + 4 * i];
            r[4 * i] = v.x * dv; r[4 * i + 1] = v.y * dv;
            r[4 * i + 2] = v.z * dv; r[4 * i + 3] = v.w * dv;
        }
        float outT[TD];
#pragma unroll
        for (int t = 0; t < TD; ++t) outT[t] = 0.f;

        const float* Wzz = sW;
        const float* Whh = sW + 512;
        const float* bzz = sW + 1024;
        const float* bhh = sW + 1088;
        const float* probs = sW + 1152;
        const float* cw = sW + 1164;

        for (int h = 0; h < HD; ++h) {
            float wz[FD], wh[FD];
#pragma unroll
            for (int f = 0; f < FD; ++f) { wz[f] = Wzz[f * 64 + h]; wh[f] = Whh[f * 64 + h]; }
            float acc = 0.f;
#pragma unroll
            for (int t = 0; t < TD; ++t) {
                float z = bzz[h], hh = bhh[h];
#pragma unroll
                for (int f = 0; f < FD; ++f) {
                    float v = r[f * TD + t];
                    z += v * wz[f];
                    hh += v * wh[f];
                }
                float Z = 1.f / (1.f + __expf(-z));              // sigmoid
                float Ht = 1.f - 2.f / (1.f + __expf(2.f * hh)); // tanh
                acc += probs[t] * (1.f - Z) * Ht;
            }
            float rel = fmaxf(acc, 0.f);
#pragma unroll
            for (int t = 0; t < TD; ++t) outT[t] += rel * cw[h * TD + t];
        }
        float* op = out + (size_t)d * TD;
#pragma unroll
        for (int t = 0; t < TD; ++t) op[t] = outT[t] + sW[1164 + 768 + t];
    }
}

extern "C" void kernel_launch(void* const* d_in, const int* in_sizes, int n_in,
                              void* d_out, int out_size, void* d_ws, size_t ws_size,
                              hipStream_t stream) {
    const float* x         = (const float*)d_in[0];
    const int*   ei        = (const int*)d_in[1];
    const float* w         = (const float*)d_in[2];
    const float* conv_w    = (const float*)d_in[3];
    const float* conv_b    = (const float*)d_in[4];
    const float* lin_w     = (const float*)d_in[5];
    const float* lin_b     = (const float*)d_in[6];
    const float* attention = (const float*)d_in[7];
    const float* cls_w     = (const float*)d_in[8];
    const float* cls_b     = (const float*)d_in[9];
    float* ws  = (float*)d_ws;
    float* out = (float*)d_out;

    int*   ghist   = (int*)(ws + OFF_GHIST);
    int*   bktbase = (int*)(ws + OFF_BASE);
    int*   cursor  = (int*)(ws + OFF_CUR);
    float* dinv    = ws + OFF_DINV;
    float* fused   = ws + OFF_FUSED;
    int2*  bedge   = (int2*)(ws + OFF_BEDGE);

    k_precompute<<<1, 256, 0, stream>>>(conv_w, conv_b, lin_w, lin_b, attention, fused);
    k_zero<<<1, 512, 0, stream>>>(ghist);
    k_hist<<<NT, 1024, 0, stream>>>(ei, ghist);
    k_scan<<<1, 512, 0, stream>>>(ghist, bktbase, cursor);
    k_place<<<NT, 1024, 0, stream>>>(ei, w, cursor, bedge);
    k_deg<<<NBUK, 256, 0, stream>>>(bktbase, bedge, dinv);
    k_spmm<<<NBUK, 384, 0, stream>>>(x, dinv, bktbase, bedge, fused, cls_w, cls_b, out);
}

// Round 6
// 248.047 us; speedup vs baseline: 4.7518x; 4.7518x over previous
//
#include <hip/hip_runtime.h>
#include <math.h>

#define NN 50000
#define FD 8
#define TD 12
#define HD 64
#define FT 96            // FD*TD floats per node
#define EE 1600000
#define NBUK 391         // ceil(NN/128) dst buckets of 128 nodes
#define TILE 16384
#define NT 98            // ceil(EE/TILE)
#define SORTCAP 5120     // LDS staging cap per bucket (mean 4096, sigma 64 -> +16s)

// ws offsets (4B units)
#define OFF_GHIST 0                      // int[NBUK]
#define OFF_BASE  512                    // int[NBUK+1]
#define OFF_CUR   1024                   // int[NBUK]
#define OFF_ROWST 2048                   // int[NN+1]
#define OFF_DINV  (2048 + NN + 16)       // float[NN]
#define OFF_FUSED (OFF_DINV + NN)        // float[1164]
#define OFF_BEDGE (OFF_FUSED + 1184)     // int2[EE] (even offset -> 8B aligned)
#define OFF_AGG   (OFF_BEDGE + 2*EE)     // float[NN*FT]
// total = OFF_AGG + 4.8M ~= 8.1M units ~= 32.5 MB

__global__ void k_precompute(const float* __restrict__ conv_w,
                             const float* __restrict__ conv_b,
                             const float* __restrict__ lin_w,
                             const float* __restrict__ lin_b,
                             const float* __restrict__ attention,
                             float* __restrict__ fused) {
    int tid = threadIdx.x;
    // Wzz (0..511): f,h -> sum_k conv_w[f][k]    * lin_w[0][k][h]
    // Whh (512..1023):    sum_k conv_w[f][128+k] * lin_w[2][k][h]
    for (int idx = tid; idx < 1024; idx += blockDim.x) {
        int sel = idx >> 9;
        int f = (idx & 511) >> 6;
        int h = idx & 63;
        const float* cw = conv_w + f * 192 + (sel ? 128 : 0);
        const float* lw = lin_w + (sel ? 2 * 128 * 64 : 0) + h;
        float s = 0.f;
        for (int k = 0; k < 64; ++k) s += cw[k] * lw[k * 64];
        fused[idx] = s;
    }
    // bzz (1024..1087), bhh (1088..1151)
    for (int idx = tid; idx < 128; idx += blockDim.x) {
        int sel = idx >> 6;
        int h = idx & 63;
        const float* cb = conv_b + (sel ? 128 : 0);
        const float* lw = lin_w + (sel ? 2 * 128 * 64 : 0) + h;
        float s = lin_b[(sel ? 2 * 64 : 0) + h];
        for (int k = 0; k < 64; ++k) s += cb[k] * lw[k * 64];
        fused[1024 + idx] = s;
    }
    // probs (1152..1163): softmax(attention)
    if (tid == 0) {
        float m = attention[0];
        for (int t = 1; t < TD; ++t) m = fmaxf(m, attention[t]);
        float e[TD], sum = 0.f;
        for (int t = 0; t < TD; ++t) { e[t] = __expf(attention[t] - m); sum += e[t]; }
        for (int t = 0; t < TD; ++t) fused[1152 + t] = e[t] / sum;
    }
}

__global__ void k_zero(int* __restrict__ ghist) {
    int i = threadIdx.x;
    if (i < NBUK) ghist[i] = 0;
}

// LDS-aggregated bucket histogram: ~NBUK global atomics per tile (not per edge)
__global__ __launch_bounds__(1024) void k_hist(const int* __restrict__ ei,
                                               int* __restrict__ ghist) {
    __shared__ int h[NBUK];
    int tid = threadIdx.x;
    for (int i = tid; i < NBUK; i += 1024) h[i] = 0;
    __syncthreads();
    int base = blockIdx.x * TILE;
    for (int i = 0; i < TILE / 1024; ++i) {
        int e = base + i * 1024 + tid;
        if (e < EE) atomicAdd(&h[ei[EE + e] >> 7], 1);
    }
    __syncthreads();
    for (int i = tid; i < NBUK; i += 1024)
        if (h[i]) atomicAdd(&ghist[i], h[i]);
}

// exclusive scan of bucket counts -> bucket bases + append cursors
__global__ void k_scan(const int* __restrict__ ghist, int* __restrict__ bktbase,
                       int* __restrict__ cursor) {
    __shared__ int s[512];
    int tid = threadIdx.x;
    int v = (tid < NBUK) ? ghist[tid] : 0;
    s[tid] = v;
    __syncthreads();
    for (int off = 1; off < 512; off <<= 1) {
        int t = (tid >= off) ? s[tid - off] : 0;
        __syncthreads();
        s[tid] += t;
        __syncthreads();
    }
    int excl = s[tid] - v;
    if (tid < NBUK) { bktbase[tid] = excl; cursor[tid] = excl; }
    if (tid == NBUK - 1) bktbase[NBUK] = excl + v;   // == EE
}

// tile claims per-bucket ranges (one global atomic per (tile,bucket)), then
// writes packed edges grouped by bucket: (src | dst_local<<16, w)
__global__ __launch_bounds__(1024) void k_place(const int* __restrict__ ei,
                                                const float* __restrict__ w,
                                                int* __restrict__ cursor,
                                                int2* __restrict__ bedge) {
    __shared__ int h[NBUK], bbase[NBUK];
    int tid = threadIdx.x;
    for (int i = tid; i < NBUK; i += 1024) h[i] = 0;
    __syncthreads();
    int base = blockIdx.x * TILE;
    for (int i = 0; i < TILE / 1024; ++i) {
        int e = base + i * 1024 + tid;
        if (e < EE) atomicAdd(&h[ei[EE + e] >> 7], 1);
    }
    __syncthreads();
    for (int i = tid; i < NBUK; i += 1024) {
        int c = h[i];
        bbase[i] = c ? atomicAdd(&cursor[i], c) : 0;
        h[i] = 0;
    }
    __syncthreads();
    for (int i = 0; i < TILE / 1024; ++i) {
        int e = base + i * 1024 + tid;
        if (e < EE) {
            int dst = ei[EE + e];
            int bk = dst >> 7;
            int rank = atomicAdd(&h[bk], 1);   // LDS rank within (tile,bucket)
            bedge[bbase[bk] + rank] =
                make_int2(ei[e] | ((dst & 127) << 16), __float_as_int(w[e]));
        }
    }
}

// per-bucket LDS counting sort by dst-local; writes back IN PLACE (block-local
// dense region), emits rowstart + dinv as by-products. Zero global atomics.
__global__ __launch_bounds__(256) void k_sort(const int* __restrict__ bktbase,
                                              int2* __restrict__ bedge,
                                              int* __restrict__ rowstart,
                                              float* __restrict__ dinv) {
    __shared__ int2 stage[SORTCAP];   // 40 KB
    __shared__ int cnt[128];
    __shared__ float wd[128];
    __shared__ int rowbase[128];
    int tid = threadIdx.x, b = blockIdx.x;
    int es = bktbase[b], ee = bktbase[b + 1];
    int count = ee - es;
    if (count > SORTCAP) count = SORTCAP;   // statistically unreachable
    if (tid < 128) { cnt[tid] = 0; wd[tid] = 0.f; }
    __syncthreads();
    for (int i = tid; i < count; i += 256) {
        int2 u = bedge[es + i];
        stage[i] = u;
        int dl = u.x >> 16;
        atomicAdd(&cnt[dl], 1);
        atomicAdd(&wd[dl], __int_as_float(u.y));
    }
    __syncthreads();
    // inclusive scan of cnt -> rowbase, then make exclusive
    if (tid < 128) rowbase[tid] = cnt[tid];
    __syncthreads();
    for (int off = 1; off < 128; off <<= 1) {
        int t = 0;
        if (tid >= off && tid < 128) t = rowbase[tid - off];
        __syncthreads();
        if (tid < 128) rowbase[tid] += t;
        __syncthreads();
    }
    int dbase = b << 7;
    if (tid < 128) {
        int excl = rowbase[tid] - cnt[tid];
        rowbase[tid] = excl;
        if (dbase + tid < NN) {
            rowstart[dbase + tid] = es + excl;
            dinv[dbase + tid] = rsqrtf(1.0f + wd[tid]);   // self-loop weight 1
        }
        cnt[tid] = 0;   // reuse as per-dst rank cursor
    }
    if (b == NBUK - 1 && tid == 0) rowstart[NN] = ee;
    __syncthreads();
    for (int i = tid; i < count; i += 256) {
        int2 u = stage[i];
        int dl = u.x >> 16;
        int pos = atomicAdd(&cnt[dl], 1);
        bedge[es + rowbase[dl] + pos] = make_int2(u.x & 0xFFFF, u.y);
    }
}

// thread = (node, float4-chunk). 24 lanes share a node -> 384B coalesced x reads.
// coeff = dinv[src]*w computed inline (broadcast dinv load across the 24 lanes).
__global__ __launch_bounds__(256) void k_gather(const float* __restrict__ x,
                                                const float* __restrict__ dinv,
                                                const int* __restrict__ rowstart,
                                                const int2* __restrict__ edata,
                                                float* __restrict__ agg) {
    unsigned t = blockIdx.x * 256u + threadIdx.x;
    if (t >= (unsigned)NN * 24u) return;
    unsigned n = t / 24u;
    unsigned c = t - n * 24u;
    const float4* x4 = (const float4*)x;
    float dv = dinv[n];
    float4 a = x4[n * 24u + c];
    a.x *= dv; a.y *= dv; a.z *= dv; a.w *= dv;   // dinv[n]*x[n]
    int rs = rowstart[n], re = rowstart[n + 1];
    for (int k = rs; k < re; ++k) {
        int2 p = edata[k];
        float co = dinv[p.x] * __int_as_float(p.y);   // dinv[s]*w
        float4 xv = x4[(unsigned)p.x * 24u + c];
        a.x += co * xv.x; a.y += co * xv.y; a.z += co * xv.z; a.w += co * xv.w;
    }
    a.x *= dv; a.y *= dv; a.z *= dv; a.w *= dv;   // outer dinv[n]
    ((float4*)agg)[n * 24u + c] = a;
}

// 4 threads per node, 16 h each; butterfly-reduce outT[12] over the 4 lanes
__global__ __launch_bounds__(256) void k_node(const float* __restrict__ agg,
                                              const float* __restrict__ fused,
                                              const float* __restrict__ cls_w,
                                              const float* __restrict__ cls_b,
                                              float* __restrict__ out) {
    __shared__ float sW[1164 + 768 + 12];
    for (int i = threadIdx.x; i < 1164 + 768; i += 256)
        sW[i] = (i < 1164) ? fused[i] : cls_w[i - 1164];
    if (threadIdx.x < 12) sW[1164 + 768 + threadIdx.x] = cls_b[threadIdx.x];
    __syncthreads();
    int n = blockIdx.x * 64 + (threadIdx.x >> 2);
    int q = threadIdx.x & 3;
    if (n >= NN) return;

    float r[FT];
    const float4* ap = (const float4*)(agg + (size_t)n * FT);
#pragma unroll
    for (int i = 0; i < FT / 4; ++i) {
        float4 v = ap[i];
        r[4 * i] = v.x; r[4 * i + 1] = v.y; r[4 * i + 2] = v.z; r[4 * i + 3] = v.w;
    }
    float outT[TD];
#pragma unroll
    for (int t = 0; t < TD; ++t) outT[t] = 0.f;

    const float* Wzz = sW;
    const float* Whh = sW + 512;
    const float* bzz = sW + 1024;
    const float* bhh = sW + 1088;
    const float* probs = sW + 1152;
    const float* cw = sW + 1164;

    for (int i = 0; i < 16; ++i) {
        int h = (q << 4) | i;
        float wz[FD], wh[FD];
#pragma unroll
        for (int f = 0; f < FD; ++f) { wz[f] = Wzz[f * 64 + h]; wh[f] = Whh[f * 64 + h]; }
        float acc = 0.f;
#pragma unroll
        for (int t = 0; t < TD; ++t) {
            float z = bzz[h], hh = bhh[h];
#pragma unroll
            for (int f = 0; f < FD; ++f) {
                float v = r[f * TD + t];
                z += v * wz[f];
                hh += v * wh[f];
            }
            float Z = 1.f / (1.f + __expf(-z));              // sigmoid
            float Ht = 1.f - 2.f / (1.f + __expf(2.f * hh)); // tanh
            acc += probs[t] * (1.f - Z) * Ht;
        }
        float rel = fmaxf(acc, 0.f);
#pragma unroll
        for (int t = 0; t < TD; ++t) outT[t] += rel * cw[h * TD + t];
    }
#pragma unroll
    for (int t = 0; t < TD; ++t) {
        outT[t] += __shfl_xor(outT[t], 1);
        outT[t] += __shfl_xor(outT[t], 2);
    }
    if (q == 0) {
        float* op = out + (size_t)n * TD;
#pragma unroll
        for (int t = 0; t < TD; ++t) op[t] = outT[t] + sW[1164 + 768 + t];
    }
}

extern "C" void kernel_launch(void* const* d_in, const int* in_sizes, int n_in,
                              void* d_out, int out_size, void* d_ws, size_t ws_size,
                              hipStream_t stream) {
    const float* x         = (const float*)d_in[0];
    const int*   ei        = (const int*)d_in[1];
    const float* w         = (const float*)d_in[2];
    const float* conv_w    = (const float*)d_in[3];
    const float* conv_b    = (const float*)d_in[4];
    const float* lin_w     = (const float*)d_in[5];
    const float* lin_b     = (const float*)d_in[6];
    const float* attention = (const float*)d_in[7];
    const float* cls_w     = (const float*)d_in[8];
    const float* cls_b     = (const float*)d_in[9];
    float* ws  = (float*)d_ws;
    float* out = (float*)d_out;

    int*   ghist    = (int*)(ws + OFF_GHIST);
    int*   bktbase  = (int*)(ws + OFF_BASE);
    int*   cursor   = (int*)(ws + OFF_CUR);
    int*   rowstart = (int*)(ws + OFF_ROWST);
    float* dinv     = ws + OFF_DINV;
    float* fused    = ws + OFF_FUSED;
    int2*  bedge    = (int2*)(ws + OFF_BEDGE);
    float* agg      = ws + OFF_AGG;

    k_precompute<<<1, 256, 0, stream>>>(conv_w, conv_b, lin_w, lin_b, attention, fused);
    k_zero<<<1, 512, 0, stream>>>(ghist);
    k_hist<<<NT, 1024, 0, stream>>>(ei, ghist);
    k_scan<<<1, 512, 0, stream>>>(ghist, bktbase, cursor);
    k_place<<<NT, 1024, 0, stream>>>(ei, w, cursor, bedge);
    k_sort<<<NBUK, 256, 0, stream>>>(bktbase, bedge, rowstart, dinv);
    {
        unsigned total = (unsigned)NN * 24u;   // 1.2M threads
        k_gather<<<(total + 255) / 256, 256, 0, stream>>>(x, dinv, rowstart, bedge, agg);
    }
    k_node<<<(NN + 63) / 64, 256, 0, stream>>>(agg, fused, cls_w, cls_b, out);
}